// Round 7
// baseline (148.728 us; speedup 1.0000x reference)
//
#include <hip/hip_runtime.h>

#define BB 16
#define LL 4096
#define DD 768
#define CB 320
#define TPB 192              // = DD/4: one float4 column per thread
#define ROWS 64              // rows per block (contiguous 192 KB chunk)
#define NCHUNK (LL / ROWS)   // 64 chunks per batch
#define NPAIR 21             // full strided pair-rounds; remainder 64 (t<64)
#define PF 8                 // rows prefetched before the histogram

// Single fused kernel. grid = BB*NCHUNK = 1024 blocks, 192 threads.
// Block (b,c): prefetch 8 x-rows -> redundant per-batch histogram (pairs in
// registers) -> sinv -> 64 pre-scaled row weights -> contiguous 192KB stream
// with register accumulation -> partial to ws -> last block per batch reduces.
__global__ __launch_bounds__(TPB) void k_all(const float* __restrict__ x,
                                             const int2* __restrict__ vq,
                                             float* __restrict__ part,
                                             int* __restrict__ done,
                                             float* __restrict__ out) {
    __shared__ int   cnt[2 * CB];
    __shared__ float wl[ROWS];
    __shared__ float wsum[TPB / 64];
    __shared__ float s_sinv;
    __shared__ int   s_last;

    const int blk = blockIdx.x;
    const int b = blk / NCHUNK;
    const int c = blk % NCHUNK;
    const int t = threadIdx.x;

    // ---- early-issue x prefetch: loads in flight during the histogram ----
    const float4* xb = (const float4*)(x + ((size_t)(b * 2 + 1) * LL +
                                            (size_t)c * ROWS) * DD);
    float4 pf[PF];
#pragma unroll
    for (int r = 0; r < PF; ++r) pf[r] = xb[(size_t)r * (DD / 4) + t];

    for (int i = t; i < 2 * CB; i += TPB) cnt[i] = 0;
    __syncthreads();

    // ---- load all pairs for batch b, packed 16+16 bits into registers ----
    const int2* vb = vq + (size_t)b * LL;
    unsigned int p[NPAIR + 1];
#pragma unroll
    for (int k = 0; k < NPAIR; ++k) {
        int2 v = vb[t + k * TPB];
        p[k] = (unsigned int)v.x | ((unsigned int)v.y << 16);
    }
    const bool has = (t < LL - NPAIR * TPB);   // t < 64
    {
        int2 v = has ? vb[t + NPAIR * TPB] : make_int2(0, 0);
        p[NPAIR] = (unsigned int)v.x | ((unsigned int)v.y << 16);
    }

    // ---- LDS histogram ----
#pragma unroll
    for (int k = 0; k < NPAIR; ++k) {
        atomicAdd(&cnt[p[k] & 0xFFFF], 1);
        atomicAdd(&cnt[CB + (p[k] >> 16)], 1);
    }
    if (has) {
        atomicAdd(&cnt[p[NPAIR] & 0xFFFF], 1);
        atomicAdd(&cnt[CB + (p[NPAIR] >> 16)], 1);
    }
    __syncthreads();

    // ---- sum of 1/(cx+cy) over all rows -> sinv ----
    float lsum = 0.f;
#pragma unroll
    for (int k = 0; k < NPAIR; ++k)
        lsum += 1.0f / (float)(cnt[p[k] & 0xFFFF] + cnt[CB + (p[k] >> 16)]);
    if (has)
        lsum += 1.0f / (float)(cnt[p[NPAIR] & 0xFFFF] + cnt[CB + (p[NPAIR] >> 16)]);
    for (int o = 32; o > 0; o >>= 1) lsum += __shfl_down(lsum, o, 64);
    if ((t & 63) == 0) wsum[t >> 6] = lsum;
    __syncthreads();
    if (t == 0) s_sinv = 1.0f / (wsum[0] + wsum[1] + wsum[2]);
    __syncthreads();

    // ---- pre-scaled weights for this block's 64 rows ----
    if (t < ROWS) {
        int2 v = vb[c * ROWS + t];             // L2-hot re-read
        wl[t] = s_sinv / (float)(cnt[v.x] + cnt[CB + v.y]);
    }
    __syncthreads();

    // ---- consume prefetched rows, then stream the rest ----
    float ax = 0.f, ay = 0.f, az = 0.f, aw = 0.f;
#pragma unroll
    for (int r = 0; r < PF; ++r) {
        const float wi = wl[r];
        ax = fmaf(wi, pf[r].x, ax);
        ay = fmaf(wi, pf[r].y, ay);
        az = fmaf(wi, pf[r].z, az);
        aw = fmaf(wi, pf[r].w, aw);
    }
#pragma unroll 8
    for (int r = PF; r < ROWS; ++r) {
        const float wi = wl[r];
        float4 v = xb[(size_t)r * (DD / 4) + t];
        ax = fmaf(wi, v.x, ax);
        ay = fmaf(wi, v.y, ay);
        az = fmaf(wi, v.z, az);
        aw = fmaf(wi, v.w, aw);
    }
    float4 o; o.x = ax; o.y = ay; o.z = az; o.w = aw;
    ((float4*)part)[(size_t)blk * (DD / 4) + t] = o;

    // ---- last-block-per-batch reduction (deterministic, fixed order) ----
    __threadfence();                 // release: all threads' partials visible
    __syncthreads();
    if (t == 0) {
        int old = atomicAdd(&done[b], 1);
        s_last = (old == NCHUNK - 1);
    }
    __syncthreads();
    if (s_last) {
        __threadfence();             // acquire: invalidate stale L1/L2 lines
        const float4* pp = (const float4*)part +
                           (size_t)b * NCHUNK * (DD / 4) + t;
        float sx = 0.f, sy = 0.f, sz = 0.f, sw = 0.f;
#pragma unroll 8
        for (int cc = 0; cc < NCHUNK; ++cc) {
            float4 v = pp[(size_t)cc * (DD / 4)];
            sx += v.x; sy += v.y; sz += v.z; sw += v.w;
        }
        float4 os; os.x = sx; os.y = sy; os.z = sz; os.w = sw;
        ((float4*)out)[(size_t)b * (DD / 4) + t] = os;
    }
}

extern "C" void kernel_launch(void* const* d_in, const int* in_sizes, int n_in,
                              void* d_out, int out_size, void* d_ws, size_t ws_size,
                              hipStream_t stream) {
    const float* x = (const float*)d_in[0];       // (16, 2, 4096, 768) fp32
    // d_in[1] = input_lengths: unused by the reference
    const int2* vq = (const int2*)d_in[2];        // (16, 4096, 2) int32

    float* part = (float*)d_ws;                   // BB*NCHUNK*DD floats = 3 MB
    int* done = (int*)(part + (size_t)BB * NCHUNK * DD);  // BB ints
    float* out = (float*)d_out;                   // (16, 768) fp32

    hipMemsetAsync(done, 0, BB * sizeof(int), stream);
    k_all<<<BB * NCHUNK, TPB, 0, stream>>>(x, vq, part, done, out);
}

// Round 8
// 41.597 us; speedup vs baseline: 3.5755x; 3.5755x over previous
//
#include <hip/hip_runtime.h>

#define BB 16
#define LL 4096
#define DD 768
#define CB 320
#define TPB 192              // = DD/4: one float4 column per thread
#define ROWS 64              // rows per block (contiguous 192 KB chunk)
#define NCHUNK (LL / ROWS)   // 64 chunks per batch

// ---------------- Kernel 0: histogram + pre-scaled weights (1 block/batch) -----
// 1024 threads, 4 pairs each, held in registers across both passes.
__global__ __launch_bounds__(1024) void k_weights(const int2* __restrict__ vq,
                                                  float* __restrict__ w) {
    __shared__ int cnt[2 * CB];
    __shared__ float wsum[16];
    __shared__ float s_sinv;
    const int b = blockIdx.x;
    const int t = threadIdx.x;

    if (t < 2 * CB) cnt[t] = 0;
    __syncthreads();

    const int2* vb = vq + (size_t)b * LL;
    int2 v[4];
#pragma unroll
    for (int k = 0; k < 4; ++k) v[k] = vb[t + k * 1024];
#pragma unroll
    for (int k = 0; k < 4; ++k) {
        atomicAdd(&cnt[v[k].x], 1);
        atomicAdd(&cnt[CB + v[k].y], 1);
    }
    __syncthreads();

    float wk[4];
    float lsum = 0.f;
#pragma unroll
    for (int k = 0; k < 4; ++k) {
        wk[k] = 1.0f / (float)(cnt[v[k].x] + cnt[CB + v[k].y]);
        lsum += wk[k];
    }
    for (int o = 32; o > 0; o >>= 1) lsum += __shfl_down(lsum, o, 64);
    if ((t & 63) == 0) wsum[t >> 6] = lsum;
    __syncthreads();
    if (t == 0) {
        float s = 0.f;
#pragma unroll
        for (int i = 0; i < 16; ++i) s += wsum[i];
        s_sinv = 1.0f / s;
    }
    __syncthreads();

    const float si = s_sinv;
#pragma unroll
    for (int k = 0; k < 4; ++k)
        w[(size_t)b * LL + t + k * 1024] = si * wk[k];
}

// ---------------- Kernel 1: contiguous weighted stream -> partials -------------
// grid = BB*NCHUNK = 1024 blocks, 192 threads. Prologue = one 256 B L2-hot
// read into LDS; then a pure 192 KB contiguous fp32 stream per block.
__global__ __launch_bounds__(TPB) void k_stream(const float* __restrict__ x,
                                                const float* __restrict__ w,
                                                float* __restrict__ part) {
    __shared__ float wl[ROWS];
    const int blk = blockIdx.x;
    const int b = blk / NCHUNK;
    const int c = blk % NCHUNK;
    const int t = threadIdx.x;

    if (t < ROWS) wl[t] = w[(size_t)b * LL + c * ROWS + t];
    __syncthreads();

    const float4* xb = (const float4*)(x + ((size_t)(b * 2 + 1) * LL +
                                            (size_t)c * ROWS) * DD);
    float ax = 0.f, ay = 0.f, az = 0.f, aw = 0.f;
#pragma unroll 8
    for (int r = 0; r < ROWS; ++r) {
        const float wi = wl[r];
        float4 v = xb[(size_t)r * (DD / 4) + t];
        ax = fmaf(wi, v.x, ax);
        ay = fmaf(wi, v.y, ay);
        az = fmaf(wi, v.z, az);
        aw = fmaf(wi, v.w, aw);
    }
    float4 o; o.x = ax; o.y = ay; o.z = az; o.w = aw;
    ((float4*)part)[(size_t)blk * (DD / 4) + t] = o;
}

// ---------------- Kernel 2: reduce partials -> out -----------------------------
// 48 blocks x 256 threads; block covers 64 (b,d4) lanes, 4 chunk-groups of 16.
__global__ __launch_bounds__(256) void k_reduce(const float* __restrict__ part,
                                                float* __restrict__ out) {
    __shared__ float4 red[3][64];
    const int t = threadIdx.x;
    const int lane = t & 63;
    const int cg = t >> 6;                        // 0..3
    const int i = blockIdx.x * 64 + lane;         // 0 .. BB*DD/4-1
    const int b = i / (DD / 4);
    const int d4 = i % (DD / 4);
    const float4* p = (const float4*)part;

    float ax = 0.f, ay = 0.f, az = 0.f, aw = 0.f;
    const int c0 = cg * (NCHUNK / 4);
#pragma unroll 8
    for (int c = c0; c < c0 + NCHUNK / 4; ++c) {
        float4 v = p[((size_t)(b * NCHUNK + c)) * (DD / 4) + d4];
        ax += v.x; ay += v.y; az += v.z; aw += v.w;
    }
    if (cg > 0) {
        float4 o; o.x = ax; o.y = ay; o.z = az; o.w = aw;
        red[cg - 1][lane] = o;
    }
    __syncthreads();
    if (cg == 0) {
        float4 r0 = red[0][lane], r1 = red[1][lane], r2 = red[2][lane];
        float4 o;
        o.x = ax + r0.x + r1.x + r2.x;
        o.y = ay + r0.y + r1.y + r2.y;
        o.z = az + r0.z + r1.z + r2.z;
        o.w = aw + r0.w + r1.w + r2.w;
        ((float4*)out)[i] = o;
    }
}

extern "C" void kernel_launch(void* const* d_in, const int* in_sizes, int n_in,
                              void* d_out, int out_size, void* d_ws, size_t ws_size,
                              hipStream_t stream) {
    const float* x = (const float*)d_in[0];       // (16, 2, 4096, 768) fp32
    // d_in[1] = input_lengths: unused by the reference
    const int2* vq = (const int2*)d_in[2];        // (16, 4096, 2) int32

    float* w = (float*)d_ws;                      // BB*LL floats (256 KB)
    float* part = w + (size_t)BB * LL;            // BB*NCHUNK*DD floats (3 MB)
    float* out = (float*)d_out;                   // (16, 768) fp32

    k_weights<<<BB, 1024, 0, stream>>>(vq, w);
    k_stream<<<BB * NCHUNK, TPB, 0, stream>>>(x, w, part);
    k_reduce<<<48, 256, 0, stream>>>(part, out);
}

// Round 9
// 39.398 us; speedup vs baseline: 3.7750x; 1.0558x over previous
//
#include <hip/hip_runtime.h>

#define BB 16
#define LL 4096
#define DD 768
#define CB 320
#define TPB 192              // = DD/4: one float4 column per thread
#define ROWS 128             // rows per block (contiguous 384 KB chunk)
#define NCHUNK (LL / ROWS)   // 32 chunks per batch
#define NPAIR 21             // full strided pair-rounds; remainder 64 (t<64)

// ---------------- Kernel 1: fused hist + sinv + weighted partial sums ----------
// grid = BB*NCHUNK = 512 blocks, 192 threads. Each block redundantly builds
// its batch's histogram (pairs packed in registers), computes sinv locally,
// derives its 128 pre-scaled row weights, then streams its CONTIGUOUS
// 384 KB x-chunk accumulating one 768-float partial.
__global__ __launch_bounds__(TPB) void k_main(const float* __restrict__ x,
                                              const int2* __restrict__ vq,
                                              float* __restrict__ part) {
    __shared__ int   cnt[2 * CB];
    __shared__ float wl[ROWS];
    __shared__ float wsum[TPB / 64];
    __shared__ float s_sinv;

    const int blk = blockIdx.x;
    const int b = blk / NCHUNK;
    const int c = blk % NCHUNK;
    const int t = threadIdx.x;

    for (int i = t; i < 2 * CB; i += TPB) cnt[i] = 0;
    __syncthreads();

    // ---- load all pairs for batch b, packed 16+16 bits into registers ----
    const int2* vb = vq + (size_t)b * LL;
    unsigned int p[NPAIR + 1];
#pragma unroll
    for (int k = 0; k < NPAIR; ++k) {
        int2 v = vb[t + k * TPB];
        p[k] = (unsigned int)v.x | ((unsigned int)v.y << 16);
    }
    const bool has = (t < LL - NPAIR * TPB);   // t < 64
    {
        int2 v = has ? vb[t + NPAIR * TPB] : make_int2(0, 0);
        p[NPAIR] = (unsigned int)v.x | ((unsigned int)v.y << 16);
    }

    // ---- LDS histogram ----
#pragma unroll
    for (int k = 0; k < NPAIR; ++k) {
        atomicAdd(&cnt[p[k] & 0xFFFF], 1);
        atomicAdd(&cnt[CB + (p[k] >> 16)], 1);
    }
    if (has) {
        atomicAdd(&cnt[p[NPAIR] & 0xFFFF], 1);
        atomicAdd(&cnt[CB + (p[NPAIR] >> 16)], 1);
    }
    __syncthreads();

    // ---- sum of 1/(cx+cy) over all rows -> sinv (pairs still in regs) ----
    float lsum = 0.f;
#pragma unroll
    for (int k = 0; k < NPAIR; ++k)
        lsum += 1.0f / (float)(cnt[p[k] & 0xFFFF] + cnt[CB + (p[k] >> 16)]);
    if (has)
        lsum += 1.0f / (float)(cnt[p[NPAIR] & 0xFFFF] + cnt[CB + (p[NPAIR] >> 16)]);
    for (int o = 32; o > 0; o >>= 1) lsum += __shfl_down(lsum, o, 64);
    if ((t & 63) == 0) wsum[t >> 6] = lsum;
    __syncthreads();
    if (t == 0) s_sinv = 1.0f / (wsum[0] + wsum[1] + wsum[2]);
    __syncthreads();

    // ---- pre-scaled weights for this block's 128 rows ----
    if (t < ROWS) {
        int2 v = vb[c * ROWS + t];             // L2-hot re-read
        wl[t] = s_sinv / (float)(cnt[v.x] + cnt[CB + v.y]);
    }
    __syncthreads();

    // ---- contiguous stream: 128 rows x 3072 B; thread t owns float4 col t ----
    const float4* xb = (const float4*)(x + ((size_t)(b * 2 + 1) * LL +
                                            (size_t)c * ROWS) * DD);
    float ax = 0.f, ay = 0.f, az = 0.f, aw = 0.f;
#pragma unroll 8
    for (int r = 0; r < ROWS; ++r) {
        const float wi = wl[r];
        float4 v = xb[(size_t)r * (DD / 4) + t];
        ax = fmaf(wi, v.x, ax);
        ay = fmaf(wi, v.y, ay);
        az = fmaf(wi, v.z, az);
        aw = fmaf(wi, v.w, aw);
    }
    float4 o; o.x = ax; o.y = ay; o.z = az; o.w = aw;
    ((float4*)part)[(size_t)blk * (DD / 4) + t] = o;
}

// ---------------- Kernel 2: reduce partials -> out -----------------------------
// 48 blocks x 256 threads; block covers 64 (b,d4) lanes, 4 chunk-groups of 8.
__global__ __launch_bounds__(256) void k_reduce(const float* __restrict__ part,
                                                float* __restrict__ out) {
    __shared__ float4 red[3][64];
    const int t = threadIdx.x;
    const int lane = t & 63;
    const int cg = t >> 6;                        // 0..3
    const int i = blockIdx.x * 64 + lane;         // 0 .. BB*DD/4-1
    const int b = i / (DD / 4);
    const int d4 = i % (DD / 4);
    const float4* p = (const float4*)part;

    float ax = 0.f, ay = 0.f, az = 0.f, aw = 0.f;
    const int c0 = cg * (NCHUNK / 4);
#pragma unroll
    for (int c = c0; c < c0 + NCHUNK / 4; ++c) {
        float4 v = p[((size_t)(b * NCHUNK + c)) * (DD / 4) + d4];
        ax += v.x; ay += v.y; az += v.z; aw += v.w;
    }
    if (cg > 0) {
        float4 o; o.x = ax; o.y = ay; o.z = az; o.w = aw;
        red[cg - 1][lane] = o;
    }
    __syncthreads();
    if (cg == 0) {
        float4 r0 = red[0][lane], r1 = red[1][lane], r2 = red[2][lane];
        float4 o;
        o.x = ax + r0.x + r1.x + r2.x;
        o.y = ay + r0.y + r1.y + r2.y;
        o.z = az + r0.z + r1.z + r2.z;
        o.w = aw + r0.w + r1.w + r2.w;
        ((float4*)out)[i] = o;
    }
}

extern "C" void kernel_launch(void* const* d_in, const int* in_sizes, int n_in,
                              void* d_out, int out_size, void* d_ws, size_t ws_size,
                              hipStream_t stream) {
    const float* x = (const float*)d_in[0];       // (16, 2, 4096, 768) fp32
    // d_in[1] = input_lengths: unused by the reference
    const int2* vq = (const int2*)d_in[2];        // (16, 4096, 2) int32

    float* part = (float*)d_ws;                   // BB*NCHUNK*DD floats = 1.5 MB
    float* out = (float*)d_out;                   // (16, 768) fp32

    k_main<<<BB * NCHUNK, TPB, 0, stream>>>(x, vq, part);
    k_reduce<<<48, 256, 0, stream>>>(part, out);
}

// Round 10
// 39.364 us; speedup vs baseline: 3.7783x; 1.0009x over previous
//
#include <hip/hip_runtime.h>

#define BB 16
#define LL 4096
#define DD 768
#define CB 320
#define TPB 192              // = DD/4: one float4 column per thread
#define ROWS 128             // rows per block (contiguous 384 KB chunk)
#define NCHUNK (LL / ROWS)   // 32 chunks per batch
#define NPAIR 21             // full strided pair-rounds; remainder 64 (t<64)
#define PF 8                 // x-rows prefetched before the histogram

// ---------------- Kernel 1: fused hist + sinv + weighted partial sums ----------
// grid = BB*NCHUNK = 512 blocks, 192 threads. Each block issues 8 x-row
// prefetch loads FIRST (HBM busy from cycle 0), then redundantly builds its
// batch's histogram (pairs packed in registers), computes sinv locally,
// derives its 128 pre-scaled row weights, consumes the prefetched rows, and
// streams the rest of its CONTIGUOUS 384 KB x-chunk into one 768-f partial.
__global__ __launch_bounds__(TPB) void k_main(const float* __restrict__ x,
                                              const int2* __restrict__ vq,
                                              float* __restrict__ part) {
    __shared__ int   cnt[2 * CB];
    __shared__ float wl[ROWS];
    __shared__ float wsum[TPB / 64];
    __shared__ float s_sinv;

    const int blk = blockIdx.x;
    const int b = blk / NCHUNK;
    const int c = blk % NCHUNK;
    const int t = threadIdx.x;

    // ---- early-issue x prefetch: loads in flight during the prologue ----
    const float4* xb = (const float4*)(x + ((size_t)(b * 2 + 1) * LL +
                                            (size_t)c * ROWS) * DD);
    float4 pf[PF];
#pragma unroll
    for (int r = 0; r < PF; ++r) pf[r] = xb[(size_t)r * (DD / 4) + t];

    for (int i = t; i < 2 * CB; i += TPB) cnt[i] = 0;
    __syncthreads();

    // ---- load all pairs for batch b, packed 16+16 bits into registers ----
    const int2* vb = vq + (size_t)b * LL;
    unsigned int p[NPAIR + 1];
#pragma unroll
    for (int k = 0; k < NPAIR; ++k) {
        int2 v = vb[t + k * TPB];
        p[k] = (unsigned int)v.x | ((unsigned int)v.y << 16);
    }
    const bool has = (t < LL - NPAIR * TPB);   // t < 64
    {
        int2 v = has ? vb[t + NPAIR * TPB] : make_int2(0, 0);
        p[NPAIR] = (unsigned int)v.x | ((unsigned int)v.y << 16);
    }

    // ---- LDS histogram ----
#pragma unroll
    for (int k = 0; k < NPAIR; ++k) {
        atomicAdd(&cnt[p[k] & 0xFFFF], 1);
        atomicAdd(&cnt[CB + (p[k] >> 16)], 1);
    }
    if (has) {
        atomicAdd(&cnt[p[NPAIR] & 0xFFFF], 1);
        atomicAdd(&cnt[CB + (p[NPAIR] >> 16)], 1);
    }
    __syncthreads();

    // ---- sum of 1/(cx+cy) over all rows -> sinv (pairs still in regs) ----
    float lsum = 0.f;
#pragma unroll
    for (int k = 0; k < NPAIR; ++k)
        lsum += 1.0f / (float)(cnt[p[k] & 0xFFFF] + cnt[CB + (p[k] >> 16)]);
    if (has)
        lsum += 1.0f / (float)(cnt[p[NPAIR] & 0xFFFF] + cnt[CB + (p[NPAIR] >> 16)]);
    for (int o = 32; o > 0; o >>= 1) lsum += __shfl_down(lsum, o, 64);
    if ((t & 63) == 0) wsum[t >> 6] = lsum;
    __syncthreads();
    if (t == 0) s_sinv = 1.0f / (wsum[0] + wsum[1] + wsum[2]);
    __syncthreads();

    // ---- pre-scaled weights for this block's 128 rows ----
    if (t < ROWS) {
        int2 v = vb[c * ROWS + t];             // L2-hot re-read
        wl[t] = s_sinv / (float)(cnt[v.x] + cnt[CB + v.y]);
    }
    __syncthreads();

    // ---- consume prefetched rows, then stream the rest ----
    float ax = 0.f, ay = 0.f, az = 0.f, aw = 0.f;
#pragma unroll
    for (int r = 0; r < PF; ++r) {
        const float wi = wl[r];
        ax = fmaf(wi, pf[r].x, ax);
        ay = fmaf(wi, pf[r].y, ay);
        az = fmaf(wi, pf[r].z, az);
        aw = fmaf(wi, pf[r].w, aw);
    }
#pragma unroll 8
    for (int r = PF; r < ROWS; ++r) {
        const float wi = wl[r];
        float4 v = xb[(size_t)r * (DD / 4) + t];
        ax = fmaf(wi, v.x, ax);
        ay = fmaf(wi, v.y, ay);
        az = fmaf(wi, v.z, az);
        aw = fmaf(wi, v.w, aw);
    }
    float4 o; o.x = ax; o.y = ay; o.z = az; o.w = aw;
    ((float4*)part)[(size_t)blk * (DD / 4) + t] = o;
}

// ---------------- Kernel 2: reduce partials -> out -----------------------------
// 48 blocks x 256 threads; block covers 64 (b,d4) lanes, 4 chunk-groups of 8.
__global__ __launch_bounds__(256) void k_reduce(const float* __restrict__ part,
                                                float* __restrict__ out) {
    __shared__ float4 red[3][64];
    const int t = threadIdx.x;
    const int lane = t & 63;
    const int cg = t >> 6;                        // 0..3
    const int i = blockIdx.x * 64 + lane;         // 0 .. BB*DD/4-1
    const int b = i / (DD / 4);
    const int d4 = i % (DD / 4);
    const float4* p = (const float4*)part;

    float ax = 0.f, ay = 0.f, az = 0.f, aw = 0.f;
    const int c0 = cg * (NCHUNK / 4);
#pragma unroll
    for (int c = c0; c < c0 + NCHUNK / 4; ++c) {
        float4 v = p[((size_t)(b * NCHUNK + c)) * (DD / 4) + d4];
        ax += v.x; ay += v.y; az += v.z; aw += v.w;
    }
    if (cg > 0) {
        float4 o; o.x = ax; o.y = ay; o.z = az; o.w = aw;
        red[cg - 1][lane] = o;
    }
    __syncthreads();
    if (cg == 0) {
        float4 r0 = red[0][lane], r1 = red[1][lane], r2 = red[2][lane];
        float4 o;
        o.x = ax + r0.x + r1.x + r2.x;
        o.y = ay + r0.y + r1.y + r2.y;
        o.z = az + r0.z + r1.z + r2.z;
        o.w = aw + r0.w + r1.w + r2.w;
        ((float4*)out)[i] = o;
    }
}

extern "C" void kernel_launch(void* const* d_in, const int* in_sizes, int n_in,
                              void* d_out, int out_size, void* d_ws, size_t ws_size,
                              hipStream_t stream) {
    const float* x = (const float*)d_in[0];       // (16, 2, 4096, 768) fp32
    // d_in[1] = input_lengths: unused by the reference
    const int2* vq = (const int2*)d_in[2];        // (16, 4096, 2) int32

    float* part = (float*)d_ws;                   // BB*NCHUNK*DD floats = 1.5 MB
    float* out = (float*)d_out;                   // (16, 768) fp32

    k_main<<<BB * NCHUNK, TPB, 0, stream>>>(x, vq, part);
    k_reduce<<<48, 256, 0, stream>>>(part, out);
}

// Round 11
// 39.223 us; speedup vs baseline: 3.7919x; 1.0036x over previous
//
#include <hip/hip_runtime.h>

#define BB 16
#define LL 4096
#define DD 768
#define CB 320
#define TPB 192              // = DD/4: one float4 column per thread
#define ROWS 128             // rows per block (contiguous 384 KB chunk)
#define HR (ROWS / 2)        // 64: dual-chain split
#define NCHUNK (LL / ROWS)   // 32 chunks per batch
#define NPAIR 21             // full strided pair-rounds; remainder 64 (t<64)

// ---------------- Kernel 1: fused hist + sinv + weighted partial sums ----------
// grid = BB*NCHUNK = 512 blocks, 192 threads. Each block redundantly builds
// its batch's histogram (pairs packed in registers), computes sinv locally,
// derives its 128 pre-scaled row weights, then streams its CONTIGUOUS
// 384 KB x-chunk with TWO interleaved row-chains (rows r and r+64) for 2x
// outstanding loads per thread.
__global__ __launch_bounds__(TPB) void k_main(const float* __restrict__ x,
                                              const int2* __restrict__ vq,
                                              float* __restrict__ part) {
    __shared__ int   cnt[2 * CB];
    __shared__ float wl[ROWS];
    __shared__ float wsum[TPB / 64];
    __shared__ float s_sinv;

    const int blk = blockIdx.x;
    const int b = blk / NCHUNK;
    const int c = blk % NCHUNK;
    const int t = threadIdx.x;

    for (int i = t; i < 2 * CB; i += TPB) cnt[i] = 0;
    __syncthreads();

    // ---- load all pairs for batch b, packed 16+16 bits into registers ----
    const int2* vb = vq + (size_t)b * LL;
    unsigned int p[NPAIR + 1];
#pragma unroll
    for (int k = 0; k < NPAIR; ++k) {
        int2 v = vb[t + k * TPB];
        p[k] = (unsigned int)v.x | ((unsigned int)v.y << 16);
    }
    const bool has = (t < LL - NPAIR * TPB);   // t < 64
    {
        int2 v = has ? vb[t + NPAIR * TPB] : make_int2(0, 0);
        p[NPAIR] = (unsigned int)v.x | ((unsigned int)v.y << 16);
    }

    // ---- LDS histogram ----
#pragma unroll
    for (int k = 0; k < NPAIR; ++k) {
        atomicAdd(&cnt[p[k] & 0xFFFF], 1);
        atomicAdd(&cnt[CB + (p[k] >> 16)], 1);
    }
    if (has) {
        atomicAdd(&cnt[p[NPAIR] & 0xFFFF], 1);
        atomicAdd(&cnt[CB + (p[NPAIR] >> 16)], 1);
    }
    __syncthreads();

    // ---- sum of 1/(cx+cy) over all rows -> sinv (pairs still in regs) ----
    float lsum = 0.f;
#pragma unroll
    for (int k = 0; k < NPAIR; ++k)
        lsum += 1.0f / (float)(cnt[p[k] & 0xFFFF] + cnt[CB + (p[k] >> 16)]);
    if (has)
        lsum += 1.0f / (float)(cnt[p[NPAIR] & 0xFFFF] + cnt[CB + (p[NPAIR] >> 16)]);
    for (int o = 32; o > 0; o >>= 1) lsum += __shfl_down(lsum, o, 64);
    if ((t & 63) == 0) wsum[t >> 6] = lsum;
    __syncthreads();
    if (t == 0) s_sinv = 1.0f / (wsum[0] + wsum[1] + wsum[2]);
    __syncthreads();

    // ---- pre-scaled weights for this block's 128 rows ----
    if (t < ROWS) {
        int2 v = vb[c * ROWS + t];             // L2-hot re-read
        wl[t] = s_sinv / (float)(cnt[v.x] + cnt[CB + v.y]);
    }
    __syncthreads();

    // ---- dual-chain contiguous stream: rows r and r+64 each iteration ----
    const float4* xb = (const float4*)(x + ((size_t)(b * 2 + 1) * LL +
                                            (size_t)c * ROWS) * DD);
    float ax = 0.f, ay = 0.f, az = 0.f, aw = 0.f;   // chain A: rows 0..63
    float bx = 0.f, by = 0.f, bz = 0.f, bw = 0.f;   // chain B: rows 64..127
#pragma unroll 8
    for (int r = 0; r < HR; ++r) {
        const float wA = wl[r];
        const float wB = wl[r + HR];
        float4 vA = xb[(size_t)r * (DD / 4) + t];
        float4 vB = xb[(size_t)(r + HR) * (DD / 4) + t];
        ax = fmaf(wA, vA.x, ax);
        ay = fmaf(wA, vA.y, ay);
        az = fmaf(wA, vA.z, az);
        aw = fmaf(wA, vA.w, aw);
        bx = fmaf(wB, vB.x, bx);
        by = fmaf(wB, vB.y, by);
        bz = fmaf(wB, vB.z, bz);
        bw = fmaf(wB, vB.w, bw);
    }
    float4 o;
    o.x = ax + bx; o.y = ay + by; o.z = az + bz; o.w = aw + bw;
    ((float4*)part)[(size_t)blk * (DD / 4) + t] = o;
}

// ---------------- Kernel 2: reduce partials -> out -----------------------------
// 48 blocks x 256 threads; block covers 64 (b,d4) lanes, 4 chunk-groups of 8.
__global__ __launch_bounds__(256) void k_reduce(const float* __restrict__ part,
                                                float* __restrict__ out) {
    __shared__ float4 red[3][64];
    const int t = threadIdx.x;
    const int lane = t & 63;
    const int cg = t >> 6;                        // 0..3
    const int i = blockIdx.x * 64 + lane;         // 0 .. BB*DD/4-1
    const int b = i / (DD / 4);
    const int d4 = i % (DD / 4);
    const float4* p = (const float4*)part;

    float ax = 0.f, ay = 0.f, az = 0.f, aw = 0.f;
    const int c0 = cg * (NCHUNK / 4);
#pragma unroll
    for (int c = c0; c < c0 + NCHUNK / 4; ++c) {
        float4 v = p[((size_t)(b * NCHUNK + c)) * (DD / 4) + d4];
        ax += v.x; ay += v.y; az += v.z; aw += v.w;
    }
    if (cg > 0) {
        float4 o; o.x = ax; o.y = ay; o.z = az; o.w = aw;
        red[cg - 1][lane] = o;
    }
    __syncthreads();
    if (cg == 0) {
        float4 r0 = red[0][lane], r1 = red[1][lane], r2 = red[2][lane];
        float4 o;
        o.x = ax + r0.x + r1.x + r2.x;
        o.y = ay + r0.y + r1.y + r2.y;
        o.z = az + r0.z + r1.z + r2.z;
        o.w = aw + r0.w + r1.w + r2.w;
        ((float4*)out)[i] = o;
    }
}

extern "C" void kernel_launch(void* const* d_in, const int* in_sizes, int n_in,
                              void* d_out, int out_size, void* d_ws, size_t ws_size,
                              hipStream_t stream) {
    const float* x = (const float*)d_in[0];       // (16, 2, 4096, 768) fp32
    // d_in[1] = input_lengths: unused by the reference
    const int2* vq = (const int2*)d_in[2];        // (16, 4096, 2) int32

    float* part = (float*)d_ws;                   // BB*NCHUNK*DD floats = 1.5 MB
    float* out = (float*)d_out;                   // (16, 768) fp32

    k_main<<<BB * NCHUNK, TPB, 0, stream>>>(x, vq, part);
    k_reduce<<<48, 256, 0, stream>>>(part, out);
}